// Round 10
// baseline (245.537 us; speedup 1.0000x reference)
//
#include <hip/hip_runtime.h>
#include <hip/hip_bf16.h>
#include <math.h>

// Problem constants (reference: B,S,D,H,FD = 2,2048,1024,16,64; DK=64, ALPHA=1)
#define Bb 2
#define Ss 2048
#define Dd 1024
#define Hh 16
#define DK 64
#define FD 64

#define LOG2E 1.4426950408889634f

typedef short short8 __attribute__((ext_vector_type(8)));   // 8 bf16 (4 VGPRs)
typedef float f32x4 __attribute__((ext_vector_type(4)));
typedef unsigned int u32;

static __device__ inline ushort f2bf(float f) {
    union { float f; unsigned u; } v; v.f = f;
    unsigned r = v.u + 0x7FFF + ((v.u >> 16) & 1);   // round-to-nearest-even
    return (ushort)(r >> 16);
}

// packed f32x2 -> bf16x2 RNE in one VALU op
static __device__ inline uint cvt_pk_bf16(float lo, float hi) {
    uint r;
    asm("v_cvt_pk_bf16_f32 %0, %1, %2" : "=v"(r) : "v"(lo), "v"(hi));
    return r;
}
static __device__ inline float fexp2(float x) {
    return __builtin_amdgcn_exp2f(x);   // v_exp_f32: D = 2^S0
}

// async global->LDS, 16B per lane; LDS dest is wave-uniform base + lane*16
static __device__ inline void gload_lds16(const ushort* g, ushort* l) {
    __builtin_amdgcn_global_load_lds((const __attribute__((address_space(1))) u32*)g,
                                     (__attribute__((address_space(3))) u32*)l, 16, 0, 0);
}

// ---------------------------------------------------------------------------
// cast fp32 -> bf16, 2 elems/thread
// ---------------------------------------------------------------------------
__global__ __launch_bounds__(256) void cast_bf16(const float* __restrict__ in,
                                                 ushort* __restrict__ out) {
    size_t p = (size_t)blockIdx.x * 256 + threadIdx.x;
    float2 v = *(const float2*)(in + 2 * p);
    ((uint*)out)[p] = (uint)f2bf(v.x) | ((uint)f2bf(v.y) << 16);
}

// ---------------------------------------------------------------------------
// transpose+cast 4 weights W[K][N] fp32 -> WT[id][N][K] bf16 (64x64 LDS tiles)
// ---------------------------------------------------------------------------
__global__ __launch_bounds__(256) void transpose_cast4(const float* __restrict__ W0,
                                                       const float* __restrict__ W1,
                                                       const float* __restrict__ W2,
                                                       const float* __restrict__ W3,
                                                       ushort* __restrict__ WT) {
    __shared__ float T[64][65];
    const float* W = blockIdx.z == 0 ? W0 : blockIdx.z == 1 ? W1 : blockIdx.z == 2 ? W2 : W3;
    ushort* dst = WT + (size_t)blockIdx.z * Dd * Dd;
    const int k0 = blockIdx.x * 64, n0 = blockIdx.y * 64;
    const int tid = threadIdx.x;
#pragma unroll
    for (int i = 0; i < 4; ++i) {
        int kr = i * 16 + (tid >> 4);
        int nc = (tid & 15) * 4;
        float4 v = *(const float4*)(W + (size_t)(k0 + kr) * Dd + n0 + nc);
        T[kr][nc] = v.x; T[kr][nc + 1] = v.y; T[kr][nc + 2] = v.z; T[kr][nc + 3] = v.w;
    }
    __syncthreads();
    int nr = tid >> 2;
    int kc = (tid & 3) * 16;
    uint pk[8];
#pragma unroll
    for (int j = 0; j < 8; ++j)
        pk[j] = (uint)f2bf(T[kc + 2 * j][nr]) | ((uint)f2bf(T[kc + 2 * j + 1][nr]) << 16);
    uint* o = (uint*)(dst + (size_t)(n0 + nr) * Dd + k0 + kc);
    *(int4*)o = *(int4*)&pk[0];
    *(int4*)(o + 4) = *(int4*)&pk[4];
}

// ---------------------------------------------------------------------------
// l2norm rows of both features->fn and requirements->rn in one launch
// ---------------------------------------------------------------------------
__global__ __launch_bounds__(256) void l2norm2(const float* __restrict__ fsrc,
                                               const float* __restrict__ rsrc,
                                               float* __restrict__ fn,
                                               float* __restrict__ rn) {
    int row = blockIdx.x * 4 + (threadIdx.x >> 6);
    int lane = threadIdx.x & 63;
    const float* in = fsrc; float* out = fn; int r = row;
    if (row >= Bb * Ss) { in = rsrc; out = rn; r = row - Bb * Ss; }
    float v = in[(size_t)r * FD + lane];
    float s = v * v;
#pragma unroll
    for (int off = 32; off; off >>= 1) s += __shfl_xor(s, off, 64);
    out[(size_t)r * FD + lane] = v / fmaxf(sqrtf(s), 1e-12f);
}

// ---------------------------------------------------------------------------
// aux halves of Qext/Kext: ext[bh][s][64:128] = rn/fn row, bf16 (coalesced)
// Qext aux is pre-scaled by log2(e) so attention can use exp2 directly.
// ---------------------------------------------------------------------------
__global__ __launch_bounds__(256) void pack_aux(const float* __restrict__ rn,
                                                const float* __restrict__ fn,
                                                ushort* __restrict__ Qext,
                                                ushort* __restrict__ Kext) {
    size_t p = (size_t)blockIdx.x * 256 + threadIdx.x;   // over B*H*S*32 uints
    int j = (int)(p & 31);
    size_t row = p >> 5;                 // bh*S + s
    int s = (int)(row & (Ss - 1));
    int bh = (int)(row >> 11);
    int b = bh >> 4;
    size_t src = ((size_t)(b * Ss + s)) * FD + j * 2;
    float2 r2 = *(const float2*)(rn + src);
    float2 f2 = *(const float2*)(fn + src);
    ((uint*)Qext)[row * 64 + 32 + j] =
        (uint)f2bf(r2.x * LOG2E) | ((uint)f2bf(r2.y * LOG2E) << 16);
    ((uint*)Kext)[row * 64 + 32 + j] = (uint)f2bf(f2.x) | ((uint)f2bf(f2.y) << 16);
}

// ---------------------------------------------------------------------------
// pack_vt: Vt[bh][d][s] = Vrow[bh][s][d]  (bf16 64x64 tile transpose via LDS)
// ---------------------------------------------------------------------------
__global__ __launch_bounds__(256) void pack_vt(const ushort* __restrict__ Vrow,
                                               ushort* __restrict__ Vt) {
    __shared__ ushort T[64][72];
    const int tid = threadIdx.x;
    const int s0 = blockIdx.x * 64;
    const int h = blockIdx.y, b = blockIdx.z;
#pragma unroll
    for (int i = 0; i < 2; ++i) {
        int f = tid + i * 256;
        int sr = f >> 3, dc = (f & 7) * 8;
        *(int4*)&T[sr][dc] =
            *(const int4*)(Vrow + ((size_t)((b * Hh + h) * Ss) + s0 + sr) * 64 + dc);
    }
    __syncthreads();
    int d = tid >> 2;
    int sg = (tid & 3) * 16;
    uint pk[8];
#pragma unroll
    for (int j = 0; j < 8; ++j)
        pk[j] = (uint)T[sg + 2 * j][d] | ((uint)T[sg + 2 * j + 1][d] << 16);
    uint* dst = (uint*)(Vt + ((size_t)((b * Hh + h) * DK + d)) * Ss + s0 + sg);
    *(int4*)dst = *(int4*)&pk[0];
    *(int4*)(dst + 4) = *(int4*)&pk[4];
}

// ---------------------------------------------------------------------------
// Fused QKV bf16 MFMA GEMM. 128x128 tile, BK=64, 4 waves.
// Round-8 VERIFIED: gload_lds staging (linear LDS, source-granule XOR
// swizzle, swizzled reads) + v8 [136]-padded epilogue overlay.
// id0 -> Qext (x 0.125*log2e), id1 -> Kext, id2 -> Vrow bf16.
// ---------------------------------------------------------------------------
__global__ __launch_bounds__(256) void gemm_qkv(const ushort* __restrict__ xb,
                                                const ushort* __restrict__ WT,
                                                const float* __restrict__ bq,
                                                const float* __restrict__ bk,
                                                const float* __restrict__ bv,
                                                ushort* __restrict__ Qext,
                                                ushort* __restrict__ Kext,
                                                ushort* __restrict__ Vrow) {
    __shared__ ushort smem[17408];        // 34.8KB: As|Bs (32KB) main, Ep epi
    ushort (*As)[64] = (ushort (*)[64])smem;            // [128][64]
    ushort (*Bs)[64] = (ushort (*)[64])(smem + 8192);   // [128][64]
    const int tid = threadIdx.x;
    const int lane = tid & 63, wave = tid >> 6;
    const int col = lane & 15, quad = lane >> 4;
    const int wm = wave >> 1, wn = wave & 1;
    const int id = blockIdx.x >> 3;               // 0:Q 1:K 2:V
    const int n0 = (blockIdx.x & 7) * 128;
    const int m0 = blockIdx.y * 128;
    const ushort* BTw = WT + (size_t)id * Dd * Dd;
    const float* bias = id == 0 ? bq : id == 1 ? bk : bv;

    const int l8 = lane >> 3;
    const int srcg = (lane & 7) ^ l8;             // r&7 == lane>>3
    const ushort* aS[4]; const ushort* bS[4];
    ushort* aD[4]; ushort* bD[4];
#pragma unroll
    for (int i = 0; i < 4; ++i) {
        int r = wave * 32 + i * 8 + l8;
        aS[i] = xb  + (size_t)(m0 + r) * Dd + srcg * 8;
        bS[i] = BTw + (size_t)(n0 + r) * Dd + srcg * 8;
        aD[i] = smem + (wave * 4 + i) * 512;
        bD[i] = smem + 8192 + (wave * 4 + i) * 512;
    }
    const int xs = col & 7;

    f32x4 acc[4][4] = {};

    for (int k0 = 0; k0 < Dd; k0 += 64) {
        __syncthreads();
#pragma unroll
        for (int i = 0; i < 4; ++i) {
            gload_lds16(aS[i] + k0, aD[i]);
            gload_lds16(bS[i] + k0, bD[i]);
        }
        __syncthreads();
#pragma unroll
        for (int kk = 0; kk < 2; ++kk) {
            short8 af[4], bf[4];
#pragma unroll
            for (int i = 0; i < 4; ++i) {
                af[i] = *(const short8*)&As[wm * 64 + i * 16 + col][((kk * 4 + quad) ^ xs) * 8];
                bf[i] = *(const short8*)&Bs[wn * 64 + i * 16 + col][((kk * 4 + quad) ^ xs) * 8];
            }
#pragma unroll
            for (int i = 0; i < 4; ++i)
#pragma unroll
                for (int j = 0; j < 4; ++j)
                    acc[i][j] = __builtin_amdgcn_mfma_f32_16x16x32_bf16(af[i], bf[j], acc[i][j], 0, 0, 0);
        }
    }

    // ---- coalesced epilogue via LDS (v8-verified, [136] padded) ----
    __syncthreads();                               // As/Bs reads all done
    ushort (*Ep)[136] = (ushort (*)[136])smem;     // 128x136 = 34.8KB
    const float scl = (id == 0) ? 0.125f * LOG2E : 1.0f;
#pragma unroll
    for (int j = 0; j < 4; ++j) {
        int n_local = wn * 64 + j * 16 + col;
        float bvl = bias[n0 + n_local];
#pragma unroll
        for (int i = 0; i < 4; ++i) {
            int mb = wm * 64 + i * 16 + quad * 4;
#pragma unroll
            for (int reg = 0; reg < 4; ++reg)
                Ep[mb + reg][n_local] = f2bf((acc[i][j][reg] + bvl) * scl);
        }
    }
    __syncthreads();
    {
        const int mrow = tid >> 1;               // 0..127 local s
        const int half = tid & 1;                // which head of the 2 in n-range
        const int b = m0 >> 11, s = (m0 & (Ss - 1)) + mrow;
        const int hh = (n0 >> 6) + half;
        if (id == 2) {
            ushort* drow = Vrow + ((size_t)(b * Hh + hh) * Ss + s) * 64;
#pragma unroll
            for (int k = 0; k < 8; ++k)
                *(int4*)(drow + k * 8) = *(int4*)&Ep[mrow][half * 64 + k * 8];
        } else {
            ushort* drow = (id == 0 ? Qext : Kext) + ((size_t)(b * Hh + hh) * Ss + s) * 128;
#pragma unroll
            for (int k = 0; k < 8; ++k)
                *(int4*)(drow + k * 8) = *(int4*)&Ep[mrow][half * 64 + k * 8];
        }
    }
}

// ---------------------------------------------------------------------------
// Output projection: out[M][N] f32 = abb(bf16) @ WoT + bo.
// Round-7 VERIFIED: gload_lds staging, linear LDS, swizzled reads, direct C.
// ---------------------------------------------------------------------------
__global__ __launch_bounds__(256) void gemm_out(const ushort* __restrict__ Ab,
                                                const ushort* __restrict__ BT,
                                                const float* __restrict__ bias,
                                                float* __restrict__ C) {
    __shared__ ushort As[128][64];
    __shared__ ushort Bs[128][64];
    const int tid = threadIdx.x;
    const int lane = tid & 63, wave = tid >> 6;
    const int col = lane & 15, quad = lane >> 4;
    const int wm = wave >> 1, wn = wave & 1;
    const int n0 = blockIdx.x * 128;
    const int m0 = blockIdx.y * 128;

    const int l8 = lane >> 3;
    const int srcg = (lane & 7) ^ l8;             // r&7 == lane>>3
    const ushort* aS[4]; const ushort* bS[4];
    ushort* aD[4]; ushort* bD[4];
#pragma unroll
    for (int i = 0; i < 4; ++i) {
        int r = wave * 32 + i * 8 + l8;
        aS[i] = Ab + (size_t)(m0 + r) * Dd + srcg * 8;
        bS[i] = BT + (size_t)(n0 + r) * Dd + srcg * 8;
        aD[i] = &As[0][0] + (wave * 4 + i) * 512;
        bD[i] = &Bs[0][0] + (wave * 4 + i) * 512;
    }
    const int xs = col & 7;

    f32x4 acc[4][4] = {};

    for (int k0 = 0; k0 < Dd; k0 += 64) {
        __syncthreads();
#pragma unroll
        for (int i = 0; i < 4; ++i) {
            gload_lds16(aS[i] + k0, aD[i]);
            gload_lds16(bS[i] + k0, bD[i]);
        }
        __syncthreads();
#pragma unroll
        for (int kk = 0; kk < 2; ++kk) {
            short8 af[4], bf[4];
#pragma unroll
            for (int i = 0; i < 4; ++i) {
                af[i] = *(const short8*)&As[wm * 64 + i * 16 + col][((kk * 4 + quad) ^ xs) * 8];
                bf[i] = *(const short8*)&Bs[wn * 64 + i * 16 + col][((kk * 4 + quad) ^ xs) * 8];
            }
#pragma unroll
            for (int i = 0; i < 4; ++i)
#pragma unroll
                for (int j = 0; j < 4; ++j)
                    acc[i][j] = __builtin_amdgcn_mfma_f32_16x16x32_bf16(af[i], bf[j], acc[i][j], 0, 0, 0);
        }
    }

#pragma unroll
    for (int j = 0; j < 4; ++j) {
        int n = n0 + wn * 64 + j * 16 + col;
        float bvl = bias[n];
#pragma unroll
        for (int i = 0; i < 4; ++i) {
#pragma unroll
            for (int reg = 0; reg < 4; ++reg) {
                int m = m0 + wm * 64 + i * 16 + quad * 4 + reg;
                C[(size_t)m * Dd + n] = acc[i][j][reg] + bvl;
            }
        }
    }
}

// ---------------------------------------------------------------------------
// Flash attention v13 = v12 (round-8 verified read/compute paths) with:
//  (1) 128-key stages: ONE barrier-pair per 128 keys (2 sub-tiles computed
//      between barriers) -> half the vmcnt(0) drains. Single-buffered,
//      two barriers per stage (verified discipline; NOT the banned dbuf).
//  (2) XCD-aware bijective decode: id&7 carries bh&7 so each XCD serves
//      4 heads (3MB K/V, L2-resident); consecutive id pairs = same head,
//      complementary qt (per-CU work uniform at 17 stage-units).
// ---------------------------------------------------------------------------
#define ABQ 128

__global__ __launch_bounds__(512) void attn_mfma13(const ushort* __restrict__ Qe,
                                                   const ushort* __restrict__ Ke,
                                                   const ushort* __restrict__ Vt,
                                                   ushort* __restrict__ Ob) {
    __shared__ ushort Ks[128][128];      // swizzled K-ext, 128 keys   32KB
    __shared__ ushort Vts[64][128];      // swizzled V^T, 128 keys     16KB
    __shared__ ushort PsT[8][16][64];    // per-wave P^T               16KB

    const int tid = threadIdx.x;
    const int wave = tid >> 6, lane = tid & 63;
    const int col = lane & 15, quad = lane >> 4;

    // XCD-aware balanced decode (bijective): id = (k<<3)|x, x -> XCD lane.
    // k = (qh<<3)|(bhi<<1)|rep; bh = bhi*8+x; qt = rep ? qh : 15-qh.
    const int id = blockIdx.x;
    const int x = id & 7;
    const int k = id >> 3;               // 0..63
    const int rep = k & 1;
    const int bhi = (k >> 1) & 3;
    const int qh = k >> 3;               // 0..7
    const int bh = bhi * 8 + x;
    const int qt = rep ? qh : (15 - qh);
    const int b = bh >> 4, h = bh & 15;
    const int q0 = qt * ABQ;
    const int rowb = q0 + wave * 16;     // this wave's 16-row strip

    // Q fragments (K=128) for this wave's strip; MFMA B operand.
    short8 qf[4];
    {
        const ushort* qp = Qe + ((size_t)bh * Ss + rowb + col) * 128 + quad * 8;
#pragma unroll
        for (int k0 = 0; k0 < 4; ++k0) qf[k0] = *(const short8*)(qp + k0 * 32);
    }

    const f32x4 zero4 = {0.f, 0.f, 0.f, 0.f};
    f32x4 oaccT[4] = {zero4, zero4, zero4, zero4};
    float lsum = 0.f;                    // per-lane: q = rowb + col

    const ushort* Kbase = Ke + (size_t)bh * Ss * 128;
    const ushort* Vbase = Vt + (size_t)bh * 64 * Ss;
    const int xsw = col & 7;             // read-side swizzle

    // gload_lds staging: LDS[r][g] = global[r][g ^ (r&7)], dest linear.
    // K: 128 rows x 16 granules = 2048 (4 insts); V: 64 x 16 = 1024 (2 insts).
    const ushort* kS[4]; ushort* kD[4];
#pragma unroll
    for (int i = 0; i < 4; ++i) {
        int G = i * 512 + tid;
        int r = G >> 4, g = G & 15;
        kS[i] = Kbase + (size_t)r * 128 + (g ^ (r & 7)) * 8;
        kD[i] = &Ks[0][0] + (i * 512 + wave * 64) * 8;
    }
    const ushort* vS[2]; ushort* vD[2];
#pragma unroll
    for (int i = 0; i < 2; ++i) {
        int G = i * 512 + tid;
        int r = G >> 4, g = G & 15;
        vS[i] = Vbase + (size_t)r * Ss + (g ^ (r & 7)) * 8;
        vD[i] = &Vts[0][0] + (i * 512 + wave * 64) * 8;
    }

    const int nst = qt + 1;              // 128-key stages (exact causal need)
    for (int t2 = 0; t2 < nst; ++t2) {
        const int j0b = t2 * 128;
        const size_t ko = (size_t)j0b * 128;
        __syncthreads();                 // prior stage's reads all done
#pragma unroll
        for (int i = 0; i < 4; ++i) gload_lds16(kS[i] + ko, kD[i]);
#pragma unroll
        for (int i = 0; i < 2; ++i) gload_lds16(vS[i] + j0b, vD[i]);
        __syncthreads();                 // vmcnt(0) drain: stage landed

#pragma unroll
        for (int sub = 0; sub < 2; ++sub) {
            const int j0 = j0b + sub * 64;
            if (j0 > rowb + 15) continue;    // sub-tile fully masked

            // S^T tiles: c tiles the KEY dim (4 x 16 keys), q = col
            f32x4 sacc[4] = {zero4, zero4, zero4, zero4};
            __builtin_amdgcn_s_setprio(1);
#pragma unroll
            for (int c = 0; c < 4; ++c)
#pragma unroll
                for (int k0 = 0; k0 < 4; ++k0) {
                    short8 kf = *(const short8*)&Ks[sub * 64 + c * 16 + col][((k0 * 4 + quad) ^ xsw) * 8];
                    sacc[c] = __builtin_amdgcn_mfma_f32_16x16x32_bf16(kf, qf[k0], sacc[c], 0, 0, 0);
                }
            __builtin_amdgcn_s_setprio(0);

            const bool diag = (j0 + 63 >= rowb);     // crosses strip's diagonal
            if (diag) {
                const int qrow_rel = rowb + col - j0;    // mask: key_rel > qrow_rel
#pragma unroll
                for (int c = 0; c < 4; ++c)
#pragma unroll
                    for (int reg = 0; reg < 4; ++reg) {
                        float s = sacc[c][reg];
                        if (c * 16 + quad * 4 + reg > qrow_rel) s = -1e9f;
                        float p = fexp2(fminf(s, 28.853901f));
                        lsum += p;
                        sacc[c][reg] = p;
                    }
            } else {
#pragma unroll
                for (int c = 0; c < 4; ++c)
#pragma unroll
                    for (int reg = 0; reg < 4; ++reg) {
                        float p = fexp2(fminf(sacc[c][reg], 28.853901f));
                        lsum += p;
                        sacc[c][reg] = p;
                    }
            }
#pragma unroll
            for (int c = 0; c < 4; ++c) {
                uint2 pk;
                pk.x = cvt_pk_bf16(sacc[c][0], sacc[c][1]);
                pk.y = cvt_pk_bf16(sacc[c][2], sacc[c][3]);
                *(uint2*)&PsT[wave][col][((c * 2 + (quad >> 1)) ^ xsw) * 8 + (quad & 1) * 4] = pk;
            }

            // PV: O^T += V^T (A) x P^T (B); per-wave LDS round-trip (DS in-order)
            __builtin_amdgcn_s_setprio(1);
#pragma unroll
            for (int k0 = 0; k0 < 2; ++k0) {
                short8 ptf = *(const short8*)&PsT[wave][col][((k0 * 4 + quad) ^ xsw) * 8];
#pragma unroll
                for (int c2 = 0; c2 < 4; ++c2) {
                    short8 vtf = *(const short8*)&Vts[c2 * 16 + col][(sub * 8 + ((k0 * 4 + quad) ^ xsw)) * 8];
                    oaccT[c2] = __builtin_amdgcn_mfma_f32_16x16x32_bf16(vtf, ptf, oaccT[c2], 0, 0, 0);
                }
            }
            __builtin_amdgcn_s_setprio(0);
        }
    }

    // epilogue: O[q][d], q = rowb+col, d = c2*16 + quad*4 + reg
    {
        float l = lsum;
        l += __shfl_xor(l, 16, 64);
        l += __shfl_xor(l, 32, 64);              // sum over the 4 quads (same col)
        const float inv = 1.f / l;
        ushort* dst = Ob + ((size_t)b * Ss + rowb + col) * Dd + h * DK + quad * 4;
#pragma unroll
        for (int c2 = 0; c2 < 4; ++c2) {
            uint2 pk;
            pk.x = cvt_pk_bf16(oaccT[c2][0] * inv, oaccT[c2][1] * inv);
            pk.y = cvt_pk_bf16(oaccT[c2][2] * inv, oaccT[c2][3] * inv);
            *(uint2*)(dst + c2 * 16) = pk;
        }
    }
}

// ---------------------------------------------------------------------------
extern "C" void kernel_launch(void* const* d_in, const int* in_sizes, int n_in,
                              void* d_out, int out_size, void* d_ws, size_t ws_size,
                              hipStream_t stream) {
    const float* x            = (const float*)d_in[0];
    const float* features     = (const float*)d_in[1];
    const float* requirements = (const float*)d_in[2];
    const float* Wq = (const float*)d_in[3];
    const float* bq = (const float*)d_in[4];
    const float* Wk = (const float*)d_in[5];
    const float* bk = (const float*)d_in[6];
    const float* Wv = (const float*)d_in[7];
    const float* bv = (const float*)d_in[8];
    const float* Wo = (const float*)d_in[9];
    const float* bo = (const float*)d_in[10];

    float* out = (float*)d_out;
    float* ws = (float*)d_ws;

    // workspace layout (float offsets)
    ushort* xb   = (ushort*)(ws);                 // [4096,1024] bf16, 8MB
    ushort* WT   = (ushort*)(ws + 2097152);       // [4][1024][1024] bf16, 8MB
    ushort* Qext = (ushort*)(ws + 4194304);       // [32][2048][128] bf16, 16MB
    ushort* Kext = (ushort*)(ws + 8388608);       // 16MB
    ushort* Vrow = (ushort*)(ws + 12582912);      // [32][2048][64] bf16, 8MB
    ushort* Vt   = (ushort*)(ws + 16777216);      // [32][64][2048] bf16, 8MB
    float*  fn   =           ws + 18874368;       // [4096][64] f32
    float*  rn   =           ws + 19136512;
    ushort* abb  = (ushort*)(ws + 12582912);      // attn out bf16, reuses Vrow (dead after pack_vt)

    cast_bf16<<<8192, 256, 0, stream>>>(x, xb);
    transpose_cast4<<<dim3(16, 16, 4), 256, 0, stream>>>(Wq, Wk, Wv, Wo, WT);
    l2norm2<<<2048, 256, 0, stream>>>(features, requirements, fn, rn);
    pack_aux<<<8192, 256, 0, stream>>>(rn, fn, Qext, Kext);

    gemm_qkv<<<dim3(24, 32), 256, 0, stream>>>(xb, WT, bq, bk, bv, Qext, Kext, Vrow);
    pack_vt<<<dim3(Ss / 64, Hh, Bb), 256, 0, stream>>>(Vrow, Vt);

    attn_mfma13<<<dim3(512), 512, 0, stream>>>(Qext, Kext, Vt, abb);

    gemm_out<<<dim3(8, 32), 256, 0, stream>>>(abb, WT + (size_t)3 * Dd * Dd, bo, out);
}

// Round 11
// 239.508 us; speedup vs baseline: 1.0252x; 1.0252x over previous
//
#include <hip/hip_runtime.h>
#include <hip/hip_bf16.h>
#include <math.h>

// Problem constants (reference: B,S,D,H,FD = 2,2048,1024,16,64; DK=64, ALPHA=1)
#define Bb 2
#define Ss 2048
#define Dd 1024
#define Hh 16
#define DK 64
#define FD 64

#define LOG2E 1.4426950408889634f

typedef short short8 __attribute__((ext_vector_type(8)));   // 8 bf16 (4 VGPRs)
typedef float f32x4 __attribute__((ext_vector_type(4)));
typedef unsigned int u32;

static __device__ inline ushort f2bf(float f) {
    union { float f; unsigned u; } v; v.f = f;
    unsigned r = v.u + 0x7FFF + ((v.u >> 16) & 1);   // round-to-nearest-even
    return (ushort)(r >> 16);
}

// packed f32x2 -> bf16x2 RNE in one VALU op
static __device__ inline uint cvt_pk_bf16(float lo, float hi) {
    uint r;
    asm("v_cvt_pk_bf16_f32 %0, %1, %2" : "=v"(r) : "v"(lo), "v"(hi));
    return r;
}
static __device__ inline float fexp2(float x) {
    return __builtin_amdgcn_exp2f(x);   // v_exp_f32: D = 2^S0
}

// async global->LDS, 16B per lane; LDS dest is wave-uniform base + lane*16
static __device__ inline void gload_lds16(const ushort* g, ushort* l) {
    __builtin_amdgcn_global_load_lds((const __attribute__((address_space(1))) u32*)g,
                                     (__attribute__((address_space(3))) u32*)l, 16, 0, 0);
}

// ---------------------------------------------------------------------------
// cast fp32 -> bf16, 2 elems/thread
// ---------------------------------------------------------------------------
__global__ __launch_bounds__(256) void cast_bf16(const float* __restrict__ in,
                                                 ushort* __restrict__ out) {
    size_t p = (size_t)blockIdx.x * 256 + threadIdx.x;
    float2 v = *(const float2*)(in + 2 * p);
    ((uint*)out)[p] = (uint)f2bf(v.x) | ((uint)f2bf(v.y) << 16);
}

// ---------------------------------------------------------------------------
// transpose+cast 4 weights W[K][N] fp32 -> WT[id][N][K] bf16 (64x64 LDS tiles)
// ---------------------------------------------------------------------------
__global__ __launch_bounds__(256) void transpose_cast4(const float* __restrict__ W0,
                                                       const float* __restrict__ W1,
                                                       const float* __restrict__ W2,
                                                       const float* __restrict__ W3,
                                                       ushort* __restrict__ WT) {
    __shared__ float T[64][65];
    const float* W = blockIdx.z == 0 ? W0 : blockIdx.z == 1 ? W1 : blockIdx.z == 2 ? W2 : W3;
    ushort* dst = WT + (size_t)blockIdx.z * Dd * Dd;
    const int k0 = blockIdx.x * 64, n0 = blockIdx.y * 64;
    const int tid = threadIdx.x;
#pragma unroll
    for (int i = 0; i < 4; ++i) {
        int kr = i * 16 + (tid >> 4);
        int nc = (tid & 15) * 4;
        float4 v = *(const float4*)(W + (size_t)(k0 + kr) * Dd + n0 + nc);
        T[kr][nc] = v.x; T[kr][nc + 1] = v.y; T[kr][nc + 2] = v.z; T[kr][nc + 3] = v.w;
    }
    __syncthreads();
    int nr = tid >> 2;
    int kc = (tid & 3) * 16;
    uint pk[8];
#pragma unroll
    for (int j = 0; j < 8; ++j)
        pk[j] = (uint)f2bf(T[kc + 2 * j][nr]) | ((uint)f2bf(T[kc + 2 * j + 1][nr]) << 16);
    uint* o = (uint*)(dst + (size_t)(n0 + nr) * Dd + k0 + kc);
    *(int4*)o = *(int4*)&pk[0];
    *(int4*)(o + 4) = *(int4*)&pk[4];
}

// ---------------------------------------------------------------------------
// l2norm rows of both features->fn and requirements->rn in one launch
// ---------------------------------------------------------------------------
__global__ __launch_bounds__(256) void l2norm2(const float* __restrict__ fsrc,
                                               const float* __restrict__ rsrc,
                                               float* __restrict__ fn,
                                               float* __restrict__ rn) {
    int row = blockIdx.x * 4 + (threadIdx.x >> 6);
    int lane = threadIdx.x & 63;
    const float* in = fsrc; float* out = fn; int r = row;
    if (row >= Bb * Ss) { in = rsrc; out = rn; r = row - Bb * Ss; }
    float v = in[(size_t)r * FD + lane];
    float s = v * v;
#pragma unroll
    for (int off = 32; off; off >>= 1) s += __shfl_xor(s, off, 64);
    out[(size_t)r * FD + lane] = v / fmaxf(sqrtf(s), 1e-12f);
}

// ---------------------------------------------------------------------------
// aux halves of Qext/Kext: ext[bh][s][64:128] = rn/fn row, bf16 (coalesced)
// Qext aux is pre-scaled by log2(e) so attention can use exp2 directly.
// ---------------------------------------------------------------------------
__global__ __launch_bounds__(256) void pack_aux(const float* __restrict__ rn,
                                                const float* __restrict__ fn,
                                                ushort* __restrict__ Qext,
                                                ushort* __restrict__ Kext) {
    size_t p = (size_t)blockIdx.x * 256 + threadIdx.x;   // over B*H*S*32 uints
    int j = (int)(p & 31);
    size_t row = p >> 5;                 // bh*S + s
    int s = (int)(row & (Ss - 1));
    int bh = (int)(row >> 11);
    int b = bh >> 4;
    size_t src = ((size_t)(b * Ss + s)) * FD + j * 2;
    float2 r2 = *(const float2*)(rn + src);
    float2 f2 = *(const float2*)(fn + src);
    ((uint*)Qext)[row * 64 + 32 + j] =
        (uint)f2bf(r2.x * LOG2E) | ((uint)f2bf(r2.y * LOG2E) << 16);
    ((uint*)Kext)[row * 64 + 32 + j] = (uint)f2bf(f2.x) | ((uint)f2bf(f2.y) << 16);
}

// ---------------------------------------------------------------------------
// pack_vt: Vt[bh][d][s] = Vrow[bh][s][d]  (bf16 64x64 tile transpose via LDS)
// ---------------------------------------------------------------------------
__global__ __launch_bounds__(256) void pack_vt(const ushort* __restrict__ Vrow,
                                               ushort* __restrict__ Vt) {
    __shared__ ushort T[64][72];
    const int tid = threadIdx.x;
    const int s0 = blockIdx.x * 64;
    const int h = blockIdx.y, b = blockIdx.z;
#pragma unroll
    for (int i = 0; i < 2; ++i) {
        int f = tid + i * 256;
        int sr = f >> 3, dc = (f & 7) * 8;
        *(int4*)&T[sr][dc] =
            *(const int4*)(Vrow + ((size_t)((b * Hh + h) * Ss) + s0 + sr) * 64 + dc);
    }
    __syncthreads();
    int d = tid >> 2;
    int sg = (tid & 3) * 16;
    uint pk[8];
#pragma unroll
    for (int j = 0; j < 8; ++j)
        pk[j] = (uint)T[sg + 2 * j][d] | ((uint)T[sg + 2 * j + 1][d] << 16);
    uint* dst = (uint*)(Vt + ((size_t)((b * Hh + h) * DK + d)) * Ss + s0 + sg);
    *(int4*)dst = *(int4*)&pk[0];
    *(int4*)(dst + 4) = *(int4*)&pk[4];
}

// ---------------------------------------------------------------------------
// Fused QKV bf16 MFMA GEMM. 128x128 tile, BK=64, 4 waves.
// Round-8 VERIFIED: gload_lds staging (linear LDS, source-granule XOR
// swizzle, swizzled reads) + v8 [136]-padded epilogue overlay.
// id0 -> Qext (x 0.125*log2e), id1 -> Kext, id2 -> Vrow bf16.
// ---------------------------------------------------------------------------
__global__ __launch_bounds__(256) void gemm_qkv(const ushort* __restrict__ xb,
                                                const ushort* __restrict__ WT,
                                                const float* __restrict__ bq,
                                                const float* __restrict__ bk,
                                                const float* __restrict__ bv,
                                                ushort* __restrict__ Qext,
                                                ushort* __restrict__ Kext,
                                                ushort* __restrict__ Vrow) {
    __shared__ ushort smem[17408];        // 34.8KB: As|Bs (32KB) main, Ep epi
    ushort (*As)[64] = (ushort (*)[64])smem;            // [128][64]
    ushort (*Bs)[64] = (ushort (*)[64])(smem + 8192);   // [128][64]
    const int tid = threadIdx.x;
    const int lane = tid & 63, wave = tid >> 6;
    const int col = lane & 15, quad = lane >> 4;
    const int wm = wave >> 1, wn = wave & 1;
    const int id = blockIdx.x >> 3;               // 0:Q 1:K 2:V
    const int n0 = (blockIdx.x & 7) * 128;
    const int m0 = blockIdx.y * 128;
    const ushort* BTw = WT + (size_t)id * Dd * Dd;
    const float* bias = id == 0 ? bq : id == 1 ? bk : bv;

    const int l8 = lane >> 3;
    const int srcg = (lane & 7) ^ l8;             // r&7 == lane>>3
    const ushort* aS[4]; const ushort* bS[4];
    ushort* aD[4]; ushort* bD[4];
#pragma unroll
    for (int i = 0; i < 4; ++i) {
        int r = wave * 32 + i * 8 + l8;
        aS[i] = xb  + (size_t)(m0 + r) * Dd + srcg * 8;
        bS[i] = BTw + (size_t)(n0 + r) * Dd + srcg * 8;
        aD[i] = smem + (wave * 4 + i) * 512;
        bD[i] = smem + 8192 + (wave * 4 + i) * 512;
    }
    const int xs = col & 7;

    f32x4 acc[4][4] = {};

    for (int k0 = 0; k0 < Dd; k0 += 64) {
        __syncthreads();
#pragma unroll
        for (int i = 0; i < 4; ++i) {
            gload_lds16(aS[i] + k0, aD[i]);
            gload_lds16(bS[i] + k0, bD[i]);
        }
        __syncthreads();
#pragma unroll
        for (int kk = 0; kk < 2; ++kk) {
            short8 af[4], bf[4];
#pragma unroll
            for (int i = 0; i < 4; ++i) {
                af[i] = *(const short8*)&As[wm * 64 + i * 16 + col][((kk * 4 + quad) ^ xs) * 8];
                bf[i] = *(const short8*)&Bs[wn * 64 + i * 16 + col][((kk * 4 + quad) ^ xs) * 8];
            }
#pragma unroll
            for (int i = 0; i < 4; ++i)
#pragma unroll
                for (int j = 0; j < 4; ++j)
                    acc[i][j] = __builtin_amdgcn_mfma_f32_16x16x32_bf16(af[i], bf[j], acc[i][j], 0, 0, 0);
        }
    }

    // ---- coalesced epilogue via LDS (v8-verified, [136] padded) ----
    __syncthreads();                               // As/Bs reads all done
    ushort (*Ep)[136] = (ushort (*)[136])smem;     // 128x136 = 34.8KB
    const float scl = (id == 0) ? 0.125f * LOG2E : 1.0f;
#pragma unroll
    for (int j = 0; j < 4; ++j) {
        int n_local = wn * 64 + j * 16 + col;
        float bvl = bias[n0 + n_local];
#pragma unroll
        for (int i = 0; i < 4; ++i) {
            int mb = wm * 64 + i * 16 + quad * 4;
#pragma unroll
            for (int reg = 0; reg < 4; ++reg)
                Ep[mb + reg][n_local] = f2bf((acc[i][j][reg] + bvl) * scl);
        }
    }
    __syncthreads();
    {
        const int mrow = tid >> 1;               // 0..127 local s
        const int half = tid & 1;                // which head of the 2 in n-range
        const int b = m0 >> 11, s = (m0 & (Ss - 1)) + mrow;
        const int hh = (n0 >> 6) + half;
        if (id == 2) {
            ushort* drow = Vrow + ((size_t)(b * Hh + hh) * Ss + s) * 64;
#pragma unroll
            for (int k = 0; k < 8; ++k)
                *(int4*)(drow + k * 8) = *(int4*)&Ep[mrow][half * 64 + k * 8];
        } else {
            ushort* drow = (id == 0 ? Qext : Kext) + ((size_t)(b * Hh + hh) * Ss + s) * 128;
#pragma unroll
            for (int k = 0; k < 8; ++k)
                *(int4*)(drow + k * 8) = *(int4*)&Ep[mrow][half * 64 + k * 8];
        }
    }
}

// ---------------------------------------------------------------------------
// Output projection: out[M][N] f32 = abb(bf16) @ WoT + bo.
// Round-7 VERIFIED: gload_lds staging, linear LDS, swizzled reads, direct C.
// ---------------------------------------------------------------------------
__global__ __launch_bounds__(256) void gemm_out(const ushort* __restrict__ Ab,
                                                const ushort* __restrict__ BT,
                                                const float* __restrict__ bias,
                                                float* __restrict__ C) {
    __shared__ ushort As[128][64];
    __shared__ ushort Bs[128][64];
    const int tid = threadIdx.x;
    const int lane = tid & 63, wave = tid >> 6;
    const int col = lane & 15, quad = lane >> 4;
    const int wm = wave >> 1, wn = wave & 1;
    const int n0 = blockIdx.x * 128;
    const int m0 = blockIdx.y * 128;

    const int l8 = lane >> 3;
    const int srcg = (lane & 7) ^ l8;             // r&7 == lane>>3
    const ushort* aS[4]; const ushort* bS[4];
    ushort* aD[4]; ushort* bD[4];
#pragma unroll
    for (int i = 0; i < 4; ++i) {
        int r = wave * 32 + i * 8 + l8;
        aS[i] = Ab + (size_t)(m0 + r) * Dd + srcg * 8;
        bS[i] = BT + (size_t)(n0 + r) * Dd + srcg * 8;
        aD[i] = &As[0][0] + (wave * 4 + i) * 512;
        bD[i] = &Bs[0][0] + (wave * 4 + i) * 512;
    }
    const int xs = col & 7;

    f32x4 acc[4][4] = {};

    for (int k0 = 0; k0 < Dd; k0 += 64) {
        __syncthreads();
#pragma unroll
        for (int i = 0; i < 4; ++i) {
            gload_lds16(aS[i] + k0, aD[i]);
            gload_lds16(bS[i] + k0, bD[i]);
        }
        __syncthreads();
#pragma unroll
        for (int kk = 0; kk < 2; ++kk) {
            short8 af[4], bf[4];
#pragma unroll
            for (int i = 0; i < 4; ++i) {
                af[i] = *(const short8*)&As[wm * 64 + i * 16 + col][((kk * 4 + quad) ^ xs) * 8];
                bf[i] = *(const short8*)&Bs[wn * 64 + i * 16 + col][((kk * 4 + quad) ^ xs) * 8];
            }
#pragma unroll
            for (int i = 0; i < 4; ++i)
#pragma unroll
                for (int j = 0; j < 4; ++j)
                    acc[i][j] = __builtin_amdgcn_mfma_f32_16x16x32_bf16(af[i], bf[j], acc[i][j], 0, 0, 0);
        }
    }

#pragma unroll
    for (int j = 0; j < 4; ++j) {
        int n = n0 + wn * 64 + j * 16 + col;
        float bvl = bias[n];
#pragma unroll
        for (int i = 0; i < 4; ++i) {
#pragma unroll
            for (int reg = 0; reg < 4; ++reg) {
                int m = m0 + wm * 64 + i * 16 + quad * 4 + reg;
                C[(size_t)m * Dd + n] = acc[i][j][reg] + bvl;
            }
        }
    }
}

// ---------------------------------------------------------------------------
// Flash attention v14 = round-8's attn_mfma12 body (verified: 40KB LDS,
// 64-key stages, gload_lds staging, two barriers/stage) with ONLY the block
// decode replaced by an XCD-aware balanced mapping:
//  - id&7 = bh&7: each XCD serves 4 heads -> 3MB K/V, L2-resident (the
//    v13-verified property; FETCH_SIZE dropped 4.1x).
//  - id and id+256 share bh and get qt-sums = 15 -> per-CU work constant
//    (restores v8's balance property that v13's decode broke).
//  qt map: rep ? (qh<4 ? qh+4 : 15-qh) : (qh<4 ? qh : 19-qh)  [bijective]
// ---------------------------------------------------------------------------
#define ABQ 128

__global__ __launch_bounds__(512) void attn_mfma14(const ushort* __restrict__ Qe,
                                                   const ushort* __restrict__ Ke,
                                                   const ushort* __restrict__ Vt,
                                                   ushort* __restrict__ Ob) {
    __shared__ ushort Ks[64][128];       // swizzled K-ext tile [key][128]  16KB
    __shared__ ushort Vts[64][64];       // swizzled V^T tile [d][64key]     8KB
    __shared__ ushort PsT[8][16][64];    // swizzled per-wave P^T [q][64]   16KB

    const int tid = threadIdx.x;
    const int wave = tid >> 6, lane = tid & 63;
    const int col = lane & 15, quad = lane >> 4;

    // XCD-aware balanced decode (bijective over 512 ids)
    const int id = blockIdx.x;
    const int x = id & 7;                // XCD lane == bh&7
    const int k = id >> 3;               // 0..63
    const int rep = k & 1;
    const int bhi = (k >> 1) & 3;        // invariant under id -> id+256
    const int qh = k >> 3;               // 0..7; id+256 -> qh+4 (mod 8 range)
    const int bh = bhi * 8 + x;
    const int qt = rep ? (qh < 4 ? qh + 4 : 15 - qh)
                       : (qh < 4 ? qh : 19 - qh);
    const int b = bh >> 4, h = bh & 15;
    const int q0 = qt * ABQ;
    const int rowb = q0 + wave * 16;     // this wave's 16-row strip

    // Q fragments (K=128) for this wave's strip; MFMA B operand.
    short8 qf[4];
    {
        const ushort* qp = Qe + ((size_t)bh * Ss + rowb + col) * 128 + quad * 8;
#pragma unroll
        for (int k0 = 0; k0 < 4; ++k0) qf[k0] = *(const short8*)(qp + k0 * 32);
    }

    const f32x4 zero4 = {0.f, 0.f, 0.f, 0.f};
    f32x4 oaccT[4] = {zero4, zero4, zero4, zero4};
    float lsum = 0.f;                    // per-lane: q = rowb + col

    const ushort* Kbase = Ke + (size_t)bh * Ss * 128;
    const ushort* Vbase = Vt + (size_t)bh * 64 * Ss;
    const int xsw = col & 7;             // read-side swizzle

    // gload_lds staging: LDS granule h of row r = global granule h^(r&7).
    // K tile 64x16 granules (2 insts/thread), V tile 64x8 granules (1 inst).
    const int Gk0 = wave * 64 + lane;            // K inst 0: granules 0..511
    const int rk0 = Gk0 >> 4, sk0 = (Gk0 & 15) ^ (rk0 & 7);
    const int Gk1 = 512 + Gk0;                   // K inst 1: granules 512..1023
    const int rk1 = Gk1 >> 4, sk1 = (Gk1 & 15) ^ (rk1 & 7);
    const int Gv = Gk0;                          // V: granules 0..511
    const int rv = Gv >> 3, sv = (Gv & 7) ^ (rv & 7);
    const ushort* ksrc0 = Kbase + (size_t)rk0 * 128 + sk0 * 8;
    const ushort* ksrc1 = Kbase + (size_t)rk1 * 128 + sk1 * 8;
    const ushort* vsrc  = Vbase + (size_t)rv * Ss + sv * 8;
    ushort* kdst0 = &Ks[0][0] + wave * 512;              // wave-uniform bases
    ushort* kdst1 = &Ks[0][0] + 4096 + wave * 512;
    ushort* vdst  = &Vts[0][0] + wave * 512;

    const int ntiles = 2 * qt + 2;
    for (int t = 0; t < ntiles; ++t) {
        const int j0 = t * 64;
        __syncthreads();                 // prior tile's reads all done
        gload_lds16(ksrc0, kdst0);   ksrc0 += 64 * 128;
        gload_lds16(ksrc1, kdst1);   ksrc1 += 64 * 128;
        gload_lds16(vsrc,  vdst);    vsrc  += 64;
        __syncthreads();                 // vmcnt(0) drain: tile staged

        if (j0 > rowb + 15) continue;    // strip fully masked for this tile

        // S^T tiles: c tiles the KEY dim (4 x 16 keys), q = col
        f32x4 sacc[4] = {zero4, zero4, zero4, zero4};
        __builtin_amdgcn_s_setprio(1);
#pragma unroll
        for (int c = 0; c < 4; ++c)
#pragma unroll
            for (int k0 = 0; k0 < 4; ++k0) {
                short8 kf = *(const short8*)&Ks[c * 16 + col][((k0 * 4 + quad) ^ xsw) * 8];
                sacc[c] = __builtin_amdgcn_mfma_f32_16x16x32_bf16(kf, qf[k0], sacc[c], 0, 0, 0);
            }
        __builtin_amdgcn_s_setprio(0);

        const bool diag = (j0 + 63 >= rowb);     // tile crosses this strip's diagonal
        if (diag) {
            const int qrow_rel = rowb + col - j0;    // mask: key_rel > qrow_rel
#pragma unroll
            for (int c = 0; c < 4; ++c)
#pragma unroll
                for (int reg = 0; reg < 4; ++reg) {
                    float s = sacc[c][reg];
                    if (c * 16 + quad * 4 + reg > qrow_rel) s = -1e9f;
                    float p = fexp2(fminf(s, 28.853901f));
                    lsum += p;
                    sacc[c][reg] = p;
                }
        } else {
#pragma unroll
            for (int c = 0; c < 4; ++c)
#pragma unroll
                for (int reg = 0; reg < 4; ++reg) {
                    float p = fexp2(fminf(sacc[c][reg], 28.853901f));
                    lsum += p;
                    sacc[c][reg] = p;
                }
        }
#pragma unroll
        for (int c = 0; c < 4; ++c) {
            uint2 pk;
            pk.x = cvt_pk_bf16(sacc[c][0], sacc[c][1]);
            pk.y = cvt_pk_bf16(sacc[c][2], sacc[c][3]);
            *(uint2*)&PsT[wave][col][((c * 2 + (quad >> 1)) ^ xsw) * 8 + (quad & 1) * 4] = pk;
        }

        // PV: O^T += V^T (A) x P^T (B); per-wave LDS round-trip (DS in-order)
        __builtin_amdgcn_s_setprio(1);
#pragma unroll
        for (int k0 = 0; k0 < 2; ++k0) {
            short8 ptf = *(const short8*)&PsT[wave][col][((k0 * 4 + quad) ^ xsw) * 8];
#pragma unroll
            for (int c2 = 0; c2 < 4; ++c2) {
                short8 vtf = *(const short8*)&Vts[c2 * 16 + col][((k0 * 4 + quad) ^ xsw) * 8];
                oaccT[c2] = __builtin_amdgcn_mfma_f32_16x16x32_bf16(vtf, ptf, oaccT[c2], 0, 0, 0);
            }
        }
        __builtin_amdgcn_s_setprio(0);
    }

    // epilogue: O[q][d], q = rowb+col, d = c2*16 + quad*4 + reg
    {
        float l = lsum;
        l += __shfl_xor(l, 16, 64);
        l += __shfl_xor(l, 32, 64);              // sum over the 4 quads (same col)
        const float inv = 1.f / l;
        ushort* dst = Ob + ((size_t)b * Ss + rowb + col) * Dd + h * DK + quad * 4;
#pragma unroll
        for (int c2 = 0; c2 < 4; ++c2) {
            uint2 pk;
            pk.x = cvt_pk_bf16(oaccT[c2][0] * inv, oaccT[c2][1] * inv);
            pk.y = cvt_pk_bf16(oaccT[c2][2] * inv, oaccT[c2][3] * inv);
            *(uint2*)(dst + c2 * 16) = pk;
        }
    }
}

// ---------------------------------------------------------------------------
extern "C" void kernel_launch(void* const* d_in, const int* in_sizes, int n_in,
                              void* d_out, int out_size, void* d_ws, size_t ws_size,
                              hipStream_t stream) {
    const float* x            = (const float*)d_in[0];
    const float* features     = (const float*)d_in[1];
    const float* requirements = (const float*)d_in[2];
    const float* Wq = (const float*)d_in[3];
    const float* bq = (const float*)d_in[4];
    const float* Wk = (const float*)d_in[5];
    const float* bk = (const float*)d_in[6];
    const float* Wv = (const float*)d_in[7];
    const float* bv = (const float*)d_in[8];
    const float* Wo = (const float*)d_in[9];
    const float* bo = (const float*)d_in[10];

    float* out = (float*)d_out;
    float* ws = (float*)d_ws;

    // workspace layout (float offsets)
    ushort* xb   = (ushort*)(ws);                 // [4096,1024] bf16, 8MB
    ushort* WT   = (ushort*)(ws + 2097152);       // [4][1024][1024] bf16, 8MB
    ushort* Qext = (ushort*)(ws + 4194304);       // [32][2048][128] bf16, 16MB
    ushort* Kext = (ushort*)(ws + 8388608);       // 16MB
    ushort* Vrow = (ushort*)(ws + 12582912);      // [32][2048][64] bf16, 8MB
    ushort* Vt   = (ushort*)(ws + 16777216);      // [32][64][2048] bf16, 8MB
    float*  fn   =           ws + 18874368;       // [4096][64] f32
    float*  rn   =           ws + 19136512;
    ushort* abb  = (ushort*)(ws + 12582912);      // attn out bf16, reuses Vrow (dead after pack_vt)

    cast_bf16<<<8192, 256, 0, stream>>>(x, xb);
    transpose_cast4<<<dim3(16, 16, 4), 256, 0, stream>>>(Wq, Wk, Wv, Wo, WT);
    l2norm2<<<2048, 256, 0, stream>>>(features, requirements, fn, rn);
    pack_aux<<<8192, 256, 0, stream>>>(rn, fn, Qext, Kext);

    gemm_qkv<<<dim3(24, 32), 256, 0, stream>>>(xb, WT, bq, bk, bv, Qext, Kext, Vrow);
    pack_vt<<<dim3(Ss / 64, Hh, Bb), 256, 0, stream>>>(Vrow, Vt);

    attn_mfma14<<<dim3(512), 512, 0, stream>>>(Qext, Kext, Vt, abb);

    gemm_out<<<dim3(8, 32), 256, 0, stream>>>(abb, WT + (size_t)3 * Dd * Dd, bo, out);
}